// Round 10
// baseline (217.580 us; speedup 1.0000x reference)
//
#include <hip/hip_runtime.h>

typedef __bf16 bf16_t;
typedef __bf16 bf16x4 __attribute__((ext_vector_type(4)));
typedef __bf16 bf16x8 __attribute__((ext_vector_type(8)));
typedef float f32x4 __attribute__((ext_vector_type(4)));

#define B_ 2
#define H_ 16
#define D_ 64
#define E_ 1024
#define QL 1024
#define KL 2048
#define SCALE_L2E 0.1803368801111204f  /* 0.125 * log2(e) — softmax in exp2 domain */
#define NEG_BIG -1e30f
#define DEFER_THR 8.0f

// ---------------- async global->LDS ----------------
__device__ __forceinline__ void gload_lds16(const void* g, void* lds) {
  auto* gp = reinterpret_cast<const __attribute__((address_space(1))) uint32_t*>(
      reinterpret_cast<uintptr_t>(g));
  auto* lp = reinterpret_cast<__attribute__((address_space(3))) uint32_t*>(
      reinterpret_cast<uintptr_t>(lds));
  __builtin_amdgcn_global_load_lds(gp, lp, 16, 0, 0);
}

// ---------------- all fp32->bf16 casts + mask prep in ONE kernel (grid 7169) ----------------
__global__ __launch_bounds__(256) void cast_all(
    const float* __restrict__ q, const float* __restrict__ k, const float* __restrict__ v,
    const float* __restrict__ wq, const float* __restrict__ wk,
    const float* __restrict__ wv, const float* __restrict__ wo,
    bf16_t* __restrict__ oq, bf16_t* __restrict__ ok, bf16_t* __restrict__ ov,
    bf16_t* __restrict__ owq, bf16_t* __restrict__ owk,
    bf16_t* __restrict__ owv, bf16_t* __restrict__ owo,
    const unsigned char* __restrict__ mraw, float* __restrict__ mbias) {
  __shared__ int flagMis, flagB0;
  int blk = blockIdx.x;
  if (blk == 7168) {  // mask prep: dtype auto-detect (int32 / uint8-bool / float32)
    int t = threadIdx.x;
    if (t == 0) { flagMis = 0; flagB0 = 0; }
    __syncthreads();
    int a = 0, c = 0;
    for (int i = t; i < B_ * KL; i += 256) {
      if (i & 3) a |= mraw[i]; else c |= mraw[i];
    }
    if (a) atomicOr(&flagMis, 1);
    if (c) atomicOr(&flagB0, 1);
    __syncthreads();
    int mode = (flagMis == 0) ? 0 : (flagB0 ? 1 : 2);
    for (int i = t; i < B_ * KL; i += 256) {
      int mv;
      if (mode == 0)      mv = ((const int*)mraw)[i];
      else if (mode == 1) mv = mraw[i];
      else                mv = (((const float*)mraw)[i] != 0.0f);
      mbias[i] = mv ? NEG_BIG : 0.0f;
    }
    return;
  }
  const float* in; bf16_t* out; int base;
  if (blk < 1024)      { in = q;  out = oq;  base = blk; }
  else if (blk < 3072) { in = k;  out = ok;  base = blk - 1024; }
  else if (blk < 5120) { in = v;  out = ov;  base = blk - 3072; }
  else if (blk < 5632) { in = wq; out = owq; base = blk - 5120; }
  else if (blk < 6144) { in = wk; out = owk; base = blk - 5632; }
  else if (blk < 6656) { in = wv; out = owv; base = blk - 6144; }
  else                 { in = wo; out = owo; base = blk - 6656; }
  size_t i = (size_t)base * 256 + threadIdx.x;
  float4 a = ((const float4*)in)[2 * i];
  float4 b = ((const float4*)in)[2 * i + 1];
  bf16x8 o;
  o[0] = (bf16_t)a.x; o[1] = (bf16_t)a.y; o[2] = (bf16_t)a.z; o[3] = (bf16_t)a.w;
  o[4] = (bf16_t)b.x; o[5] = (bf16_t)b.y; o[6] = (bf16_t)b.z; o[7] = (bf16_t)b.w;
  ((bf16x8*)out)[i] = o;
}

// ---------------- fused Q/K/V projection GEMMs, one launch (grid 640) ----------------
__global__ __launch_bounds__(256, 2)
void qkv_gemm(const bf16_t* __restrict__ Xq, const bf16_t* __restrict__ Xk,
              const bf16_t* __restrict__ Xv, const bf16_t* __restrict__ Wqb,
              const bf16_t* __restrict__ Wkb, const bf16_t* __restrict__ Wvb,
              const float* __restrict__ bq, const float* __restrict__ bk,
              const float* __restrict__ bv,
              bf16_t* __restrict__ qhd, bf16_t* __restrict__ khd, bf16_t* __restrict__ vht) {
  __shared__ alignas(16) bf16_t As[2][128 * 64];
  __shared__ alignas(16) bf16_t Bs[2][128 * 64];
  const int wid = blockIdx.x;
  const int work = (wid & 7) * 80 + (wid >> 3);  // XCD-chunked (640 = 8*80)

  const bf16_t *A, *W;
  const float* bias;
  bf16_t* out;
  int mode, Lshift, row0, col0;
  if (work < 128) {
    A = Xq; W = Wqb; bias = bq; out = qhd; mode = 0; Lshift = 10;
    row0 = (work >> 3) * 128; col0 = (work & 7) * 128;
  } else if (work < 384) {
    int t = work - 128;
    A = Xk; W = Wkb; bias = bk; out = khd; mode = 0; Lshift = 11;
    row0 = (t >> 3) * 128; col0 = (t & 7) * 128;
  } else {
    int t = work - 384;
    A = Wvb; W = Xv; bias = bv; out = vht; mode = 2; Lshift = 0;
    row0 = (t & 7) * 128; col0 = (t >> 3) * 128;
  }

  const int K = 1024;
  const int tid = threadIdx.x;
  const int lane = tid & 63;
  const int w = tid >> 6;
  const int l15 = lane & 15, l4 = lane >> 4;
  const int wr = w >> 1, wc = w & 1;

  f32x4 acc[4][4] = {};

  auto stage = [&](int buf, int kt) {
    const int k0 = kt * 64;
#pragma unroll
    for (int i = 0; i < 4; ++i) {
      int idx = (w * 4 + i) * 64 + lane;
      int r = idx >> 3, c = idx & 7;
      int cs = ((c ^ (r & 7)) * 8);
      gload_lds16(A + (size_t)(row0 + r) * K + k0 + cs, &As[buf][(w * 4 + i) * 512]);
      gload_lds16(W + (size_t)(col0 + r) * K + k0 + cs, &Bs[buf][(w * 4 + i) * 512]);
    }
  };

  auto compute = [&](int buf) {
#pragma unroll
    for (int t = 0; t < 2; ++t) {
      bf16x8 af[4], bfv[4];
#pragma unroll
      for (int i = 0; i < 4; ++i) {
        int r = wr * 64 + i * 16 + l15;
        af[i] = *(const bf16x8*)&As[buf][r * 64 + (((t * 4 + l4) ^ (r & 7)) * 8)];
      }
#pragma unroll
      for (int j = 0; j < 4; ++j) {
        int r = wc * 64 + j * 16 + l15;
        bfv[j] = *(const bf16x8*)&Bs[buf][r * 64 + (((t * 4 + l4) ^ (r & 7)) * 8)];
      }
#pragma unroll
      for (int i = 0; i < 4; ++i)
#pragma unroll
        for (int j = 0; j < 4; ++j)
          acc[i][j] = __builtin_amdgcn_mfma_f32_16x16x32_bf16(af[i], bfv[j], acc[i][j], 0, 0, 0);
    }
  };

  stage(0, 0);
  const int nk = K >> 6;
  for (int kt = 0; kt < nk; ++kt) {
    __syncthreads();
    if (kt + 1 < nk) stage((kt + 1) & 1, kt + 1);
    compute(kt & 1);
  }

#pragma unroll
  for (int i = 0; i < 4; ++i) {
    int mbase = row0 + wr * 64 + i * 16 + l4 * 4;
    f32x4 bvm = {};
    if (mode == 2) bvm = *(const f32x4*)&bias[mbase];
#pragma unroll
    for (int j = 0; j < 4; ++j) {
      int n = col0 + wc * 64 + j * 16 + l15;
      float bv = (mode == 2) ? 0.f : bias[n];
#pragma unroll
      for (int r = 0; r < 4; ++r) {
        float v = acc[i][j][r] + ((mode == 2) ? bvm[r] : bv);
        int m = mbase + r;
        if (mode == 0) {
          int bi = m >> Lshift;
          int ml = m & ((1 << Lshift) - 1);
          size_t dst = ((((size_t)bi * H_ + (n >> 6)) << Lshift) + ml) * D_ + (n & 63);
          out[dst] = (bf16_t)v;
        } else {
          int hh = m >> 6, d = m & 63;
          int bi = n >> 11, kk = n & (KL - 1);
          out[((((size_t)bi * H_ + hh) << 6) + d) * KL + kk] = (bf16_t)v;
        }
      }
    }
  }
}

// ---------------- fused flash attention, 2-way KV-split ----------------
// grid 1024 = 32 bh x 2 halves x 16 q-tiles, XCD-chunked. 256 thr = 4 waves x
// 16 q-rows (QBLK=64). LDS 40KB -> 4 blocks/CU. Unnormalized O + m,l partials.
__global__ __launch_bounds__(256, 4)
void attn_fused(const bf16_t* __restrict__ qh, const bf16_t* __restrict__ kh,
                const bf16_t* __restrict__ vhT, const float* __restrict__ mbias,
                float* __restrict__ opart, float* __restrict__ marr,
                float* __restrict__ larr) {
  __shared__ alignas(16) bf16_t Ksm[2][64 * 64];
  __shared__ alignas(16) bf16_t Vt[2][64 * 64];
  __shared__ alignas(16) bf16_t Ps[4][16 * 64];

  const int wid = blockIdx.x;
  const int work = (wid & 7) * 128 + (wid >> 3);  // 1024 = 8*128 bijective
  const int qt = work & 15;
  const int half = (work >> 4) & 1;
  const int bh = work >> 5;
  const int b = bh >> 4;

  const int tid = threadIdx.x, lane = tid & 63, w = tid >> 6;
  const int l15 = lane & 15, l4 = lane >> 4;

  const bf16_t* qbase = qh + ((size_t)bh * QL + qt * 64 + w * 16) * D_;
  bf16x8 qf[2];
#pragma unroll
  for (int t = 0; t < 2; ++t)
    qf[t] = *(const bf16x8*)(qbase + l15 * D_ + t * 32 + l4 * 8);

  float m_run = NEG_BIG, l_run = 0.f;
  f32x4 o_acc[4] = {};

  // staging pointers: thread handles chunks tid and tid+256 of each 512-chunk tile
  const bf16_t* kbase = kh + ((size_t)bh * KL + half * (KL / 2)) * D_;
  const bf16_t* vtb = vhT + (size_t)bh * D_ * KL + half * (KL / 2);
  const int idx0 = tid, idx1 = tid + 256;
  const int r0 = idx0 >> 3, cs0 = ((idx0 & 7) ^ (r0 & 7)) * 8;
  const int r1 = idx1 >> 3, cs1 = ((idx1 & 7) ^ (r1 & 7)) * 8;
  const bf16_t* kp0 = kbase + r0 * D_ + cs0;
  const bf16_t* kp1 = kbase + r1 * D_ + cs1;
  const bf16_t* vp0 = vtb + (size_t)r0 * KL + cs0;
  const bf16_t* vp1 = vtb + (size_t)r1 * KL + cs1;
  const float* mptr = mbias + (size_t)b * KL + half * (KL / 2) + l4 * 4;

  auto stage = [&](int bufsel) {
    gload_lds16(kp0, &Ksm[bufsel][idx0 * 8]);
    gload_lds16(kp1, &Ksm[bufsel][idx1 * 8]);
    gload_lds16(vp0, &Vt[bufsel][idx0 * 8]);
    gload_lds16(vp1, &Vt[bufsel][idx1 * 8]);
    kp0 += 64 * D_; kp1 += 64 * D_; vp0 += 64; vp1 += 64;
  };

  stage(0);
  __syncthreads();

  const int NT = KL / 2 / 64;  // 16 tiles per half
  for (int kt = 0; kt < NT; ++kt) {
    const int buf = kt & 1;
    if (kt + 1 < NT) stage(buf ^ 1);

    f32x4 mv[4];
#pragma unroll
    for (int ct = 0; ct < 4; ++ct)
      mv[ct] = *(const f32x4*)(mptr + ct * 16);
    mptr += 64;

    // S^T = K Q^T
    f32x4 s[4] = {};
    __builtin_amdgcn_s_setprio(1);
#pragma unroll
    for (int ct = 0; ct < 4; ++ct) {
      int krow = ct * 16 + l15;
#pragma unroll
      for (int t = 0; t < 2; ++t) {
        bf16x8 kf = *(const bf16x8*)&Ksm[buf][krow * 64 + (((t * 4 + l4) ^ (krow & 7)) * 8)];
        s[ct] = __builtin_amdgcn_mfma_f32_16x16x32_bf16(kf, qf[t], s[ct], 0, 0, 0);
      }
    }
    __builtin_amdgcn_s_setprio(0);

    // per-lane online softmax for q = l15 (exp2 domain), defer-max
    float sv[4][4];
    float mt = NEG_BIG;
#pragma unroll
    for (int ct = 0; ct < 4; ++ct)
#pragma unroll
      for (int r = 0; r < 4; ++r) {
        float x = s[ct][r] * SCALE_L2E + mv[ct][r];
        sv[ct][r] = x;
        mt = fmaxf(mt, x);
      }

    if (!__all(mt <= m_run + DEFER_THR)) {
      mt = fmaxf(mt, __shfl_xor(mt, 16, 64));
      mt = fmaxf(mt, __shfl_xor(mt, 32, 64));
      float mnew = fmaxf(m_run, mt);
      float alpha = exp2f(m_run - mnew);
      m_run = mnew;
      l_run *= alpha;
      float arow[4];
#pragma unroll
      for (int r = 0; r < 4; ++r) arow[r] = __shfl(alpha, l4 * 4 + r, 64);
#pragma unroll
      for (int dt = 0; dt < 4; ++dt)
#pragma unroll
        for (int r = 0; r < 4; ++r) o_acc[dt][r] *= arow[r];
    }

    float rsum = 0.f;
#pragma unroll
    for (int ct = 0; ct < 4; ++ct)
#pragma unroll
      for (int r = 0; r < 4; ++r) {
        float p = exp2f(sv[ct][r] - m_run);
        sv[ct][r] = p;
        rsum += p;
      }
    l_run += rsum;  // per-lane partial; cross-lane reduce at end

    // P store: row q=l15, k-chunk (ct*4+l4) XOR-swizzled, b64 writes
    char* psrow = (char*)&Ps[w][0] + l15 * 128;
#pragma unroll
    for (int ct = 0; ct < 4; ++ct) {
      bf16x4 pk;
#pragma unroll
      for (int r = 0; r < 4; ++r) pk[r] = (bf16_t)sv[ct][r];
      *(bf16x4*)(psrow + (((ct * 4 + l4) ^ l15) * 8)) = pk;
    }

    // O += P V
    __builtin_amdgcn_s_setprio(1);
#pragma unroll
    for (int t = 0; t < 2; ++t) {
      int c0 = t * 8 + l4 * 2;
      bf16x4 plo = *(const bf16x4*)(psrow + ((c0 ^ l15) * 8));
      bf16x4 phi = *(const bf16x4*)(psrow + (((c0 + 1) ^ l15) * 8));
      bf16x8 pa;
#pragma unroll
      for (int j = 0; j < 4; ++j) { pa[j] = plo[j]; pa[j + 4] = phi[j]; }
#pragma unroll
      for (int dt = 0; dt < 4; ++dt) {
        int d = dt * 16 + l15;
        bf16x8 vf = *(const bf16x8*)&Vt[buf][d * 64 + (((t * 4 + l4) ^ (d & 7)) * 8)];
        o_acc[dt] = __builtin_amdgcn_mfma_f32_16x16x32_bf16(pa, vf, o_acc[dt], 0, 0, 0);
      }
    }
    __builtin_amdgcn_s_setprio(0);
    __syncthreads();
  }

  // cross-lane l reduction (4 lanes per q)
  float l_tot = l_run + __shfl_xor(l_run, 16, 64);
  l_tot += __shfl_xor(l_tot, 32, 64);

  // store unnormalized partials
  const size_t prow = (size_t)(half * 32 + bh) * QL;
#pragma unroll
  for (int r = 0; r < 4; ++r) {
    int qrow = qt * 64 + w * 16 + l4 * 4 + r;
#pragma unroll
    for (int dt = 0; dt < 4; ++dt) {
      int d = dt * 16 + l15;
      opart[(prow + qrow) * D_ + d] = o_acc[dt][r];
    }
  }
  if (l4 == 0) {
    int q = qt * 64 + w * 16 + l15;
    marr[prow + q] = m_run;
    larr[prow + q] = l_tot;
  }
}

// ---------------- O-projection GEMM with fused softmax-merge ----------------
// out[m][n] = sum_e axo[m][e] * Wo[n][e] + bo[n], axo merged on the fly.
// 64x128 tiles -> grid 256 (1 block/CU), XCD-chunked. BK=64 = one head per
// K-step, so merge scalars (m0,m1,l0,l1) are per-row lookups at head kt.
// A: reg-staged f32 partials -> merge -> bf16 swizzled LDS. B: DMA dbuf.
__global__ __launch_bounds__(256)
void oproj_merge(const float* __restrict__ opart, const float* __restrict__ marr,
                 const float* __restrict__ larr, const bf16_t* __restrict__ Wob,
                 const float* __restrict__ bo, float* __restrict__ out) {
  __shared__ alignas(16) bf16_t As[64 * 64];
  __shared__ alignas(16) bf16_t Bs[2][128 * 64];
  const int wid = blockIdx.x;
  const int work = (wid & 7) * 32 + (wid >> 3);  // 256 = 8*32 bijective
  const int rt = work >> 3, ct = work & 7;
  const int row0 = rt * 64, col0 = ct * 128;
  const int tid = threadIdx.x, lane = tid & 63, w = tid >> 6;
  const int l15 = lane & 15, l4 = lane >> 4;

  // A staging: thread t -> row ar=t>>2, 16 cols from ac=(t&3)*16
  const int ar = tid >> 2, ac = (tid & 3) * 16;
  const int gm = row0 + ar;
  const int b = gm >> 10, q = gm & 1023;

  f32x4 acc[8] = {};
  f32x4 a0[4], a1[4];
  float sm0, sm1, sl0, sl1;

  auto stageB = [&](int buf, int kt) {
#pragma unroll
    for (int i = 0; i < 4; ++i) {
      int idx = (w * 4 + i) * 64 + lane;
      int r = idx >> 3, c = idx & 7;
      int cs = ((c ^ (r & 7)) * 8);
      gload_lds16(Wob + (size_t)(col0 + r) * E_ + kt * 64 + cs, &Bs[buf][idx * 8]);
    }
  };

  auto loadA = [&](int kt) {  // head = kt
    size_t r0 = (((size_t)b * 16 + kt) << 10) + q;
    size_t r1 = r0 + 32768;
    const f32x4* p0 = (const f32x4*)&opart[r0 * 64 + ac];
    const f32x4* p1 = (const f32x4*)&opart[r1 * 64 + ac];
#pragma unroll
    for (int i = 0; i < 4; ++i) { a0[i] = p0[i]; a1[i] = p1[i]; }
    sm0 = marr[r0]; sm1 = marr[r1]; sl0 = larr[r0]; sl1 = larr[r1];
  };

  auto writeA = [&]() {
    float m = fmaxf(sm0, sm1);
    float w0 = exp2f(sm0 - m), w1 = exp2f(sm1 - m);
    float denom = sl0 * w0 + sl1 * w1;
    float s0 = w0 / denom, s1 = w1 / denom;
#pragma unroll
    for (int hh = 0; hh < 2; ++hh) {
      bf16x8 ov;
#pragma unroll
      for (int j = 0; j < 8; ++j) {
        int e = hh * 8 + j;
        float v = a0[e >> 2][e & 3] * s0 + a1[e >> 2][e & 3] * s1;
        ov[j] = (bf16_t)v;
      }
      int c = (ac >> 3) + hh;
      *(bf16x8*)&As[ar * 64 + (((c ^ (ar & 7)) * 8))] = ov;
    }
  };

  loadA(0);
  stageB(0, 0);
  for (int kt = 0; kt < 16; ++kt) {
    writeA();              // publish merged A(kt) (regs -> LDS)
    __syncthreads();       // A visible; B(kt) DMA drained (own vmcnt)
    if (kt < 15) { loadA(kt + 1); stageB((kt + 1) & 1, kt + 1); }

    const int buf = kt & 1;
#pragma unroll
    for (int t = 0; t < 2; ++t) {
      int r = w * 16 + l15;
      bf16x8 af = *(const bf16x8*)&As[r * 64 + (((t * 4 + l4) ^ (r & 7)) * 8)];
#pragma unroll
      for (int j = 0; j < 8; ++j) {
        int br = j * 16 + l15;
        bf16x8 bfv = *(const bf16x8*)&Bs[buf][br * 64 + (((t * 4 + l4) ^ (br & 7)) * 8)];
        acc[j] = __builtin_amdgcn_mfma_f32_16x16x32_bf16(af, bfv, acc[j], 0, 0, 0);
      }
    }
    __syncthreads();       // everyone done reading As/Bs[buf]
  }

#pragma unroll
  for (int j = 0; j < 8; ++j) {
    int n = col0 + j * 16 + l15;
    float bv = bo[n];
#pragma unroll
    for (int r = 0; r < 4; ++r) {
      int m = row0 + w * 16 + l4 * 4 + r;
      out[(size_t)m * E_ + n] = acc[j][r] + bv;
    }
  }
}

// ---------------- host ----------------
extern "C" void kernel_launch(void* const* d_in, const int* in_sizes, int n_in,
                              void* d_out, int out_size, void* d_ws, size_t ws_size,
                              hipStream_t stream) {
  const float* query = (const float*)d_in[0];
  const float* key   = (const float*)d_in[1];
  const float* value = (const float*)d_in[2];
  const void*  mask  = d_in[3];
  const float* Wq = (const float*)d_in[4];
  const float* bq = (const float*)d_in[5];
  const float* Wk = (const float*)d_in[6];
  const float* bk = (const float*)d_in[7];
  const float* Wv = (const float*)d_in[8];
  const float* bv = (const float*)d_in[9];
  const float* Wo = (const float*)d_in[10];
  const float* bo = (const float*)d_in[11];

  char* ws = (char*)d_ws;
  bf16_t* Xq  = (bf16_t*)(ws + (0ull  << 20));  // 4 MB   (dead after qkv_gemm)
  bf16_t* Xk  = (bf16_t*)(ws + (4ull  << 20));  // 8 MB
  bf16_t* Xv  = (bf16_t*)(ws + (12ull << 20));  // 8 MB
  bf16_t* Wqb = (bf16_t*)(ws + (20ull << 20));  // 2 MB
  bf16_t* Wkb = (bf16_t*)(ws + (22ull << 20));
  bf16_t* Wvb = (bf16_t*)(ws + (24ull << 20));
  bf16_t* Wob = (bf16_t*)(ws + (26ull << 20));
  bf16_t* qhd = (bf16_t*)(ws + (28ull << 20));  // 4 MB  [B,H,QL,D]
  bf16_t* khd = (bf16_t*)(ws + (32ull << 20));  // 8 MB  [B,H,KL,D]
  bf16_t* vht = (bf16_t*)(ws + (40ull << 20));  // 8 MB  [B,H,D,KL]  (V^T)
  float*  mbias = (float*)(ws + (52ull << 20)); // 16 KB
  // attn partials reuse the Xq/Xk/Xv region (dead once attn_fused launches)
  float* opart = (float*)(ws + (0ull << 20));   // 16 MB [2][32][1024][64] f32
  float* marr  = (float*)(ws + (16ull << 20));  // 256 KB [2][32][1024]
  float* larr  = (float*)(ws + (17ull << 20));  // 256 KB

  cast_all<<<7169, 256, 0, stream>>>(query, key, value, Wq, Wk, Wv, Wo,
                                     Xq, Xk, Xv, Wqb, Wkb, Wvb, Wob,
                                     (const unsigned char*)mask, mbias);
  qkv_gemm<<<640, 256, 0, stream>>>(Xq, Xk, Xv, Wqb, Wkb, Wvb, bq, bk, bv,
                                    qhd, khd, vht);
  attn_fused<<<1024, 256, 0, stream>>>(qhd, khd, vht, mbias, opart, marr, larr);
  oproj_merge<<<256, 256, 0, stream>>>(opart, marr, larr, Wob, bo, (float*)d_out);
}

// Round 11
// 211.403 us; speedup vs baseline: 1.0292x; 1.0292x over previous
//
#include <hip/hip_runtime.h>

typedef __bf16 bf16_t;
typedef __bf16 bf16x4 __attribute__((ext_vector_type(4)));
typedef __bf16 bf16x8 __attribute__((ext_vector_type(8)));
typedef float f32x4 __attribute__((ext_vector_type(4)));

#define B_ 2
#define H_ 16
#define D_ 64
#define E_ 1024
#define QL 1024
#define KL 2048
#define SCALE_L2E 0.1803368801111204f  /* 0.125 * log2(e) — softmax in exp2 domain */
#define NEG_BIG -1e30f
#define DEFER_THR 8.0f

// ---------------- async global->LDS ----------------
__device__ __forceinline__ void gload_lds16(const void* g, void* lds) {
  auto* gp = reinterpret_cast<const __attribute__((address_space(1))) uint32_t*>(
      reinterpret_cast<uintptr_t>(g));
  auto* lp = reinterpret_cast<__attribute__((address_space(3))) uint32_t*>(
      reinterpret_cast<uintptr_t>(lds));
  __builtin_amdgcn_global_load_lds(gp, lp, 16, 0, 0);
}

// ---------------- all fp32->bf16 casts + mask prep in ONE kernel (grid 7169) ----------------
__global__ __launch_bounds__(256) void cast_all(
    const float* __restrict__ q, const float* __restrict__ k, const float* __restrict__ v,
    const float* __restrict__ wq, const float* __restrict__ wk,
    const float* __restrict__ wv, const float* __restrict__ wo,
    bf16_t* __restrict__ oq, bf16_t* __restrict__ ok, bf16_t* __restrict__ ov,
    bf16_t* __restrict__ owq, bf16_t* __restrict__ owk,
    bf16_t* __restrict__ owv, bf16_t* __restrict__ owo,
    const unsigned char* __restrict__ mraw, float* __restrict__ mbias) {
  __shared__ int flagMis, flagB0;
  int blk = blockIdx.x;
  if (blk == 7168) {  // mask prep: dtype auto-detect (int32 / uint8-bool / float32)
    int t = threadIdx.x;
    if (t == 0) { flagMis = 0; flagB0 = 0; }
    __syncthreads();
    int a = 0, c = 0;
    for (int i = t; i < B_ * KL; i += 256) {
      if (i & 3) a |= mraw[i]; else c |= mraw[i];
    }
    if (a) atomicOr(&flagMis, 1);
    if (c) atomicOr(&flagB0, 1);
    __syncthreads();
    int mode = (flagMis == 0) ? 0 : (flagB0 ? 1 : 2);
    for (int i = t; i < B_ * KL; i += 256) {
      int mv;
      if (mode == 0)      mv = ((const int*)mraw)[i];
      else if (mode == 1) mv = mraw[i];
      else                mv = (((const float*)mraw)[i] != 0.0f);
      mbias[i] = mv ? NEG_BIG : 0.0f;
    }
    return;
  }
  const float* in; bf16_t* out; int base;
  if (blk < 1024)      { in = q;  out = oq;  base = blk; }
  else if (blk < 3072) { in = k;  out = ok;  base = blk - 1024; }
  else if (blk < 5120) { in = v;  out = ov;  base = blk - 3072; }
  else if (blk < 5632) { in = wq; out = owq; base = blk - 5120; }
  else if (blk < 6144) { in = wk; out = owk; base = blk - 5632; }
  else if (blk < 6656) { in = wv; out = owv; base = blk - 6144; }
  else                 { in = wo; out = owo; base = blk - 6656; }
  size_t i = (size_t)base * 256 + threadIdx.x;
  float4 a = ((const float4*)in)[2 * i];
  float4 b = ((const float4*)in)[2 * i + 1];
  bf16x8 o;
  o[0] = (bf16_t)a.x; o[1] = (bf16_t)a.y; o[2] = (bf16_t)a.z; o[3] = (bf16_t)a.w;
  o[4] = (bf16_t)b.x; o[5] = (bf16_t)b.y; o[6] = (bf16_t)b.z; o[7] = (bf16_t)b.w;
  ((bf16x8*)out)[i] = o;
}

// ---------------- fused Q/K/V projection GEMMs, one launch (grid 640) ----------------
__global__ __launch_bounds__(256, 2)
void qkv_gemm(const bf16_t* __restrict__ Xq, const bf16_t* __restrict__ Xk,
              const bf16_t* __restrict__ Xv, const bf16_t* __restrict__ Wqb,
              const bf16_t* __restrict__ Wkb, const bf16_t* __restrict__ Wvb,
              const float* __restrict__ bq, const float* __restrict__ bk,
              const float* __restrict__ bv,
              bf16_t* __restrict__ qhd, bf16_t* __restrict__ khd, bf16_t* __restrict__ vht) {
  __shared__ alignas(16) bf16_t As[2][128 * 64];
  __shared__ alignas(16) bf16_t Bs[2][128 * 64];
  const int wid = blockIdx.x;
  const int work = (wid & 7) * 80 + (wid >> 3);  // XCD-chunked (640 = 8*80)

  const bf16_t *A, *W;
  const float* bias;
  bf16_t* out;
  int mode, Lshift, row0, col0;
  if (work < 128) {
    A = Xq; W = Wqb; bias = bq; out = qhd; mode = 0; Lshift = 10;
    row0 = (work >> 3) * 128; col0 = (work & 7) * 128;
  } else if (work < 384) {
    int t = work - 128;
    A = Xk; W = Wkb; bias = bk; out = khd; mode = 0; Lshift = 11;
    row0 = (t >> 3) * 128; col0 = (t & 7) * 128;
  } else {
    int t = work - 384;
    A = Wvb; W = Xv; bias = bv; out = vht; mode = 2; Lshift = 0;
    row0 = (t & 7) * 128; col0 = (t >> 3) * 128;
  }

  const int K = 1024;
  const int tid = threadIdx.x;
  const int lane = tid & 63;
  const int w = tid >> 6;
  const int l15 = lane & 15, l4 = lane >> 4;
  const int wr = w >> 1, wc = w & 1;

  f32x4 acc[4][4] = {};

  auto stage = [&](int buf, int kt) {
    const int k0 = kt * 64;
#pragma unroll
    for (int i = 0; i < 4; ++i) {
      int idx = (w * 4 + i) * 64 + lane;
      int r = idx >> 3, c = idx & 7;
      int cs = ((c ^ (r & 7)) * 8);
      gload_lds16(A + (size_t)(row0 + r) * K + k0 + cs, &As[buf][(w * 4 + i) * 512]);
      gload_lds16(W + (size_t)(col0 + r) * K + k0 + cs, &Bs[buf][(w * 4 + i) * 512]);
    }
  };

  auto compute = [&](int buf) {
#pragma unroll
    for (int t = 0; t < 2; ++t) {
      bf16x8 af[4], bfv[4];
#pragma unroll
      for (int i = 0; i < 4; ++i) {
        int r = wr * 64 + i * 16 + l15;
        af[i] = *(const bf16x8*)&As[buf][r * 64 + (((t * 4 + l4) ^ (r & 7)) * 8)];
      }
#pragma unroll
      for (int j = 0; j < 4; ++j) {
        int r = wc * 64 + j * 16 + l15;
        bfv[j] = *(const bf16x8*)&Bs[buf][r * 64 + (((t * 4 + l4) ^ (r & 7)) * 8)];
      }
#pragma unroll
      for (int i = 0; i < 4; ++i)
#pragma unroll
        for (int j = 0; j < 4; ++j)
          acc[i][j] = __builtin_amdgcn_mfma_f32_16x16x32_bf16(af[i], bfv[j], acc[i][j], 0, 0, 0);
    }
  };

  stage(0, 0);
  const int nk = K >> 6;
  for (int kt = 0; kt < nk; ++kt) {
    __syncthreads();
    if (kt + 1 < nk) stage((kt + 1) & 1, kt + 1);
    compute(kt & 1);
  }

#pragma unroll
  for (int i = 0; i < 4; ++i) {
    int mbase = row0 + wr * 64 + i * 16 + l4 * 4;
    f32x4 bvm = {};
    if (mode == 2) bvm = *(const f32x4*)&bias[mbase];
#pragma unroll
    for (int j = 0; j < 4; ++j) {
      int n = col0 + wc * 64 + j * 16 + l15;
      float bv = (mode == 2) ? 0.f : bias[n];
#pragma unroll
      for (int r = 0; r < 4; ++r) {
        float v = acc[i][j][r] + ((mode == 2) ? bvm[r] : bv);
        int m = mbase + r;
        if (mode == 0) {
          int bi = m >> Lshift;
          int ml = m & ((1 << Lshift) - 1);
          size_t dst = ((((size_t)bi * H_ + (n >> 6)) << Lshift) + ml) * D_ + (n & 63);
          out[dst] = (bf16_t)v;
        } else {
          int hh = m >> 6, d = m & 63;
          int bi = n >> 11, kk = n & (KL - 1);
          out[((((size_t)bi * H_ + hh) << 6) + d) * KL + kk] = (bf16_t)v;
        }
      }
    }
  }
}

// ---------------- fused flash attention, 2-way KV-split ----------------
// grid 1024 = 32 bh x 2 halves x 16 q-tiles, XCD-chunked. 256 thr = 4 waves x
// 16 q-rows (QBLK=64). LDS 40KB. Unnormalized O + m,l partials.
__global__ __launch_bounds__(256, 4)
void attn_fused(const bf16_t* __restrict__ qh, const bf16_t* __restrict__ kh,
                const bf16_t* __restrict__ vhT, const float* __restrict__ mbias,
                float* __restrict__ opart, float* __restrict__ marr,
                float* __restrict__ larr) {
  __shared__ alignas(16) bf16_t Ksm[2][64 * 64];
  __shared__ alignas(16) bf16_t Vt[2][64 * 64];
  __shared__ alignas(16) bf16_t Ps[4][16 * 64];

  const int wid = blockIdx.x;
  const int work = (wid & 7) * 128 + (wid >> 3);  // 1024 = 8*128 bijective
  const int qt = work & 15;
  const int half = (work >> 4) & 1;
  const int bh = work >> 5;
  const int b = bh >> 4;

  const int tid = threadIdx.x, lane = tid & 63, w = tid >> 6;
  const int l15 = lane & 15, l4 = lane >> 4;

  const bf16_t* qbase = qh + ((size_t)bh * QL + qt * 64 + w * 16) * D_;
  bf16x8 qf[2];
#pragma unroll
  for (int t = 0; t < 2; ++t)
    qf[t] = *(const bf16x8*)(qbase + l15 * D_ + t * 32 + l4 * 8);

  float m_run = NEG_BIG, l_run = 0.f;
  f32x4 o_acc[4] = {};

  // staging pointers: thread handles chunks tid and tid+256 of each 512-chunk tile
  const bf16_t* kbase = kh + ((size_t)bh * KL + half * (KL / 2)) * D_;
  const bf16_t* vtb = vhT + (size_t)bh * D_ * KL + half * (KL / 2);
  const int idx0 = tid, idx1 = tid + 256;
  const int r0 = idx0 >> 3, cs0 = ((idx0 & 7) ^ (r0 & 7)) * 8;
  const int r1 = idx1 >> 3, cs1 = ((idx1 & 7) ^ (r1 & 7)) * 8;
  const bf16_t* kp0 = kbase + r0 * D_ + cs0;
  const bf16_t* kp1 = kbase + r1 * D_ + cs1;
  const bf16_t* vp0 = vtb + (size_t)r0 * KL + cs0;
  const bf16_t* vp1 = vtb + (size_t)r1 * KL + cs1;
  const float* mptr = mbias + (size_t)b * KL + half * (KL / 2) + l4 * 4;

  auto stage = [&](int bufsel) {
    gload_lds16(kp0, &Ksm[bufsel][idx0 * 8]);
    gload_lds16(kp1, &Ksm[bufsel][idx1 * 8]);
    gload_lds16(vp0, &Vt[bufsel][idx0 * 8]);
    gload_lds16(vp1, &Vt[bufsel][idx1 * 8]);
    kp0 += 64 * D_; kp1 += 64 * D_; vp0 += 64; vp1 += 64;
  };

  stage(0);
  __syncthreads();

  const int NT = KL / 2 / 64;  // 16 tiles per half
  for (int kt = 0; kt < NT; ++kt) {
    const int buf = kt & 1;
    if (kt + 1 < NT) stage(buf ^ 1);

    f32x4 mv[4];
#pragma unroll
    for (int ct = 0; ct < 4; ++ct)
      mv[ct] = *(const f32x4*)(mptr + ct * 16);
    mptr += 64;

    // S^T = K Q^T
    f32x4 s[4] = {};
    __builtin_amdgcn_s_setprio(1);
#pragma unroll
    for (int ct = 0; ct < 4; ++ct) {
      int krow = ct * 16 + l15;
#pragma unroll
      for (int t = 0; t < 2; ++t) {
        bf16x8 kf = *(const bf16x8*)&Ksm[buf][krow * 64 + (((t * 4 + l4) ^ (krow & 7)) * 8)];
        s[ct] = __builtin_amdgcn_mfma_f32_16x16x32_bf16(kf, qf[t], s[ct], 0, 0, 0);
      }
    }
    __builtin_amdgcn_s_setprio(0);

    // per-lane online softmax for q = l15 (exp2 domain), defer-max
    float sv[4][4];
    float mt = NEG_BIG;
#pragma unroll
    for (int ct = 0; ct < 4; ++ct)
#pragma unroll
      for (int r = 0; r < 4; ++r) {
        float x = s[ct][r] * SCALE_L2E + mv[ct][r];
        sv[ct][r] = x;
        mt = fmaxf(mt, x);
      }

    if (!__all(mt <= m_run + DEFER_THR)) {
      mt = fmaxf(mt, __shfl_xor(mt, 16, 64));
      mt = fmaxf(mt, __shfl_xor(mt, 32, 64));
      float mnew = fmaxf(m_run, mt);
      float alpha = exp2f(m_run - mnew);
      m_run = mnew;
      l_run *= alpha;
      float arow[4];
#pragma unroll
      for (int r = 0; r < 4; ++r) arow[r] = __shfl(alpha, l4 * 4 + r, 64);
#pragma unroll
      for (int dt = 0; dt < 4; ++dt)
#pragma unroll
        for (int r = 0; r < 4; ++r) o_acc[dt][r] *= arow[r];
    }

    float rsum = 0.f;
#pragma unroll
    for (int ct = 0; ct < 4; ++ct)
#pragma unroll
      for (int r = 0; r < 4; ++r) {
        float p = exp2f(sv[ct][r] - m_run);
        sv[ct][r] = p;
        rsum += p;
      }
    l_run += rsum;  // per-lane partial; cross-lane reduce at end

    // P store: row q=l15, k-chunk (ct*4+l4) XOR-swizzled, b64 writes
    char* psrow = (char*)&Ps[w][0] + l15 * 128;
#pragma unroll
    for (int ct = 0; ct < 4; ++ct) {
      bf16x4 pk;
#pragma unroll
      for (int r = 0; r < 4; ++r) pk[r] = (bf16_t)sv[ct][r];
      *(bf16x4*)(psrow + (((ct * 4 + l4) ^ l15) * 8)) = pk;
    }

    // O += P V
    __builtin_amdgcn_s_setprio(1);
#pragma unroll
    for (int t = 0; t < 2; ++t) {
      int c0 = t * 8 + l4 * 2;
      bf16x4 plo = *(const bf16x4*)(psrow + ((c0 ^ l15) * 8));
      bf16x4 phi = *(const bf16x4*)(psrow + (((c0 + 1) ^ l15) * 8));
      bf16x8 pa;
#pragma unroll
      for (int j = 0; j < 4; ++j) { pa[j] = plo[j]; pa[j + 4] = phi[j]; }
#pragma unroll
      for (int dt = 0; dt < 4; ++dt) {
        int d = dt * 16 + l15;
        bf16x8 vf = *(const bf16x8*)&Vt[buf][d * 64 + (((t * 4 + l4) ^ (d & 7)) * 8)];
        o_acc[dt] = __builtin_amdgcn_mfma_f32_16x16x32_bf16(pa, vf, o_acc[dt], 0, 0, 0);
      }
    }
    __builtin_amdgcn_s_setprio(0);
    __syncthreads();
  }

  // cross-lane l reduction (4 lanes per q)
  float l_tot = l_run + __shfl_xor(l_run, 16, 64);
  l_tot += __shfl_xor(l_tot, 32, 64);

  // store unnormalized partials
  const size_t prow = (size_t)(half * 32 + bh) * QL;
#pragma unroll
  for (int r = 0; r < 4; ++r) {
    int qrow = qt * 64 + w * 16 + l4 * 4 + r;
#pragma unroll
    for (int dt = 0; dt < 4; ++dt) {
      int d = dt * 16 + l15;
      opart[(prow + qrow) * D_ + d] = o_acc[dt][r];
    }
  }
  if (l4 == 0) {
    int q = qt * 64 + w * 16 + l15;
    marr[prow + q] = m_run;
    larr[prow + q] = l_tot;
  }
}

// ---------------- merge the two KV-halves -> axo bf16 [B,QL,E] ----------------
__global__ __launch_bounds__(256)
void attn_merge(const float* __restrict__ opart, const float* __restrict__ marr,
                const float* __restrict__ larr, bf16_t* __restrict__ axo) {
  int idx = blockIdx.x * 256 + threadIdx.x;  // 262144 threads
  int row = idx >> 3;        // bh*1024 + q
  int dseg = (idx & 7) * 8;
  int bh = row >> 10, q = row & 1023;
  int b = bh >> 4, h = bh & 15;
  float m0 = marr[row], m1 = marr[32768 + row];
  float l0 = larr[row], l1 = larr[32768 + row];
  float m = fmaxf(m0, m1);
  float w0 = exp2f(m0 - m), w1 = exp2f(m1 - m);
  float denom = l0 * w0 + l1 * w1;
  float s0 = w0 / denom, s1 = w1 / denom;
  const f32x4* p0 = (const f32x4*)&opart[(size_t)row * 64 + dseg];
  const f32x4* p1 = (const f32x4*)&opart[(size_t)(32768 + row) * 64 + dseg];
  f32x4 a0 = p0[0], a1 = p0[1];
  f32x4 b0 = p1[0], b1 = p1[1];
  bf16x8 o;
#pragma unroll
  for (int i = 0; i < 4; ++i) {
    o[i]     = (bf16_t)(a0[i] * s0 + b0[i] * s1);
    o[i + 4] = (bf16_t)(a1[i] * s0 + b1[i] * s1);
  }
  *(bf16x8*)&axo[((size_t)b * QL + q) * E_ + h * 64 + dseg] = o;
}

// ---------------- O projection: 64x128 tiles, grid 256 (1 block/CU), XCD-chunked ----------------
__global__ __launch_bounds__(256)
void oproj(const bf16_t* __restrict__ A, const bf16_t* __restrict__ W,
           const float* __restrict__ bias, float* __restrict__ out) {
  __shared__ alignas(16) bf16_t As[2][64 * 64];
  __shared__ alignas(16) bf16_t Bs[2][128 * 64];
  const int wid = blockIdx.x;
  const int work = (wid & 7) * 32 + (wid >> 3);  // 256 = 8*32 bijective
  const int row0 = (work >> 3) * 64, col0 = (work & 7) * 128;
  const int tid = threadIdx.x, lane = tid & 63, w = tid >> 6;
  const int l15 = lane & 15, l4 = lane >> 4;

  f32x4 acc[8] = {};

  auto stage = [&](int buf, int kt) {
    const int k0 = kt * 64;
#pragma unroll
    for (int i = 0; i < 2; ++i) {  // A: 512 chunks
      int idx = i * 256 + tid;
      int r = idx >> 3, c = idx & 7;
      int cs = ((c ^ (r & 7)) * 8);
      gload_lds16(A + (size_t)(row0 + r) * E_ + k0 + cs, &As[buf][idx * 8]);
    }
#pragma unroll
    for (int i = 0; i < 4; ++i) {  // B: 1024 chunks
      int idx = i * 256 + tid;
      int r = idx >> 3, c = idx & 7;
      int cs = ((c ^ (r & 7)) * 8);
      gload_lds16(W + (size_t)(col0 + r) * E_ + k0 + cs, &Bs[buf][idx * 8]);
    }
  };

  stage(0, 0);
  for (int kt = 0; kt < 16; ++kt) {
    __syncthreads();
    if (kt + 1 < 16) stage((kt + 1) & 1, kt + 1);
    const int buf = kt & 1;
#pragma unroll
    for (int t = 0; t < 2; ++t) {
      int r = w * 16 + l15;
      bf16x8 af = *(const bf16x8*)&As[buf][r * 64 + (((t * 4 + l4) ^ (r & 7)) * 8)];
#pragma unroll
      for (int j = 0; j < 8; ++j) {
        int br = j * 16 + l15;
        bf16x8 bfv = *(const bf16x8*)&Bs[buf][br * 64 + (((t * 4 + l4) ^ (br & 7)) * 8)];
        acc[j] = __builtin_amdgcn_mfma_f32_16x16x32_bf16(af, bfv, acc[j], 0, 0, 0);
      }
    }
  }

#pragma unroll
  for (int j = 0; j < 8; ++j) {
    int n = col0 + j * 16 + l15;
    float bv = bias[n];
#pragma unroll
    for (int r = 0; r < 4; ++r) {
      int m = row0 + w * 16 + l4 * 4 + r;
      out[(size_t)m * E_ + n] = acc[j][r] + bv;
    }
  }
}

// ---------------- host ----------------
extern "C" void kernel_launch(void* const* d_in, const int* in_sizes, int n_in,
                              void* d_out, int out_size, void* d_ws, size_t ws_size,
                              hipStream_t stream) {
  const float* query = (const float*)d_in[0];
  const float* key   = (const float*)d_in[1];
  const float* value = (const float*)d_in[2];
  const void*  mask  = d_in[3];
  const float* Wq = (const float*)d_in[4];
  const float* bq = (const float*)d_in[5];
  const float* Wk = (const float*)d_in[6];
  const float* bk = (const float*)d_in[7];
  const float* Wv = (const float*)d_in[8];
  const float* bv = (const float*)d_in[9];
  const float* Wo = (const float*)d_in[10];
  const float* bo = (const float*)d_in[11];

  char* ws = (char*)d_ws;
  bf16_t* Xq  = (bf16_t*)(ws + (0ull  << 20));  // 4 MB   (dead after qkv_gemm)
  bf16_t* Xk  = (bf16_t*)(ws + (4ull  << 20));  // 8 MB
  bf16_t* Xv  = (bf16_t*)(ws + (12ull << 20));  // 8 MB
  bf16_t* Wqb = (bf16_t*)(ws + (20ull << 20));  // 2 MB
  bf16_t* Wkb = (bf16_t*)(ws + (22ull << 20));
  bf16_t* Wvb = (bf16_t*)(ws + (24ull << 20));
  bf16_t* Wob = (bf16_t*)(ws + (26ull << 20));
  bf16_t* qhd = (bf16_t*)(ws + (28ull << 20));  // 4 MB  [B,H,QL,D]
  bf16_t* khd = (bf16_t*)(ws + (32ull << 20));  // 8 MB  [B,H,KL,D]
  bf16_t* vht = (bf16_t*)(ws + (40ull << 20));  // 8 MB  [B,H,D,KL]  (V^T)
  bf16_t* axo = (bf16_t*)(ws + (48ull << 20));  // 4 MB  [2048][1024]
  float*  mbias = (float*)(ws + (52ull << 20)); // 16 KB
  // attn partials reuse the Xq/Xk/Xv region (dead once attn_fused launches)
  float* opart = (float*)(ws + (0ull << 20));   // 16 MB [2][32][1024][64] f32
  float* marr  = (float*)(ws + (16ull << 20));  // 256 KB [2][32][1024]
  float* larr  = (float*)(ws + (17ull << 20));  // 256 KB

  cast_all<<<7169, 256, 0, stream>>>(query, key, value, Wq, Wk, Wv, Wo,
                                     Xq, Xk, Xv, Wqb, Wkb, Wvb, Wob,
                                     (const unsigned char*)mask, mbias);
  qkv_gemm<<<640, 256, 0, stream>>>(Xq, Xk, Xv, Wqb, Wkb, Wvb, bq, bk, bv,
                                    qhd, khd, vht);
  attn_fused<<<1024, 256, 0, stream>>>(qhd, khd, vht, mbias, opart, marr, larr);
  attn_merge<<<1024, 256, 0, stream>>>(opart, marr, larr, axo);
  oproj<<<256, 256, 0, stream>>>(axo, Wob, bo, (float*)d_out);
}